// Round 5
// baseline (309.526 us; speedup 1.0000x reference)
//
#include <hip/hip_runtime.h>

// Problem constants (B, C, H, W = 64, 2048, 24, 8; NUM_IDS = 751)
#define BB 64
#define CC 2048
#define HWN 192          // H*W
#define HW4 48           // HW in float4
#define NCHUNK 16        // channel chunks per sample
#define CCHUNK 128       // CC / NCHUNK
#define TPB 384          // 8 channel-lanes x 48 hw4 positions; 6 waves/block
#define CLANES 8         // TPB / HW4

// native vector type (HIP float4 is a class; nontemporal builtin needs this)
typedef float f32x4 __attribute__((ext_vector_type(4)));

// ws layout (floats): partial[64*16*192] | cnt[64] (int)
#define PART_OFF 0
#define CNT_OFF  (BB * NCHUNK * HWN)   // 196608 floats

// Single fused kernel. grid = 1024 (b*16 + k), block = 384.
// __launch_bounds__(384,6) guarantees >=6 waves/EU = 4 blocks/CU -> all 1024
// blocks co-resident (256 CUs) -> per-sample spin is deadlock-free.
__global__ void __launch_bounds__(TPB, 6) fused_kernel(
    const float* __restrict__ f,
    const float* __restrict__ w,
    const int* __restrict__ pids,
    float* __restrict__ out,
    float* __restrict__ ws)
{
    float* partial = ws + PART_OFF;
    int*   cnt     = (int*)(ws + CNT_OFF);

    const int blk = blockIdx.x;
    const int b = blk >> 4;            // sample
    const int k = blk & (NCHUNK - 1);  // channel chunk
    const int tid = threadIdx.x;       // 0..383
    const int hw4 = tid % HW4;         // 0..47
    const int cl  = tid / HW4;         // 0..7

    __shared__ float wsm[CCHUNK];
    __shared__ __align__(16) f32x4 red[TPB];   // 6 KB scratch (reused)
    __shared__ __align__(16) float hl[HWN];
    __shared__ float s_mn, s_mx;

    const int row = pids[b];
    if (tid < CCHUNK) wsm[tid] = w[(size_t)row * CC + (size_t)k * CCHUNK + tid];
    __syncthreads();

    const size_t base = ((size_t)b * CC + (size_t)k * CCHUNK) * HW4;  // float4 units
    const f32x4* fb4 = (const f32x4*)f + base;

    // ---- Phase 1: partial dot over this 128-channel chunk ----
    f32x4 acc = (f32x4)(0.f);
#pragma unroll
    for (int i = 0; i < CCHUNK / CLANES; ++i) {        // 16 linear loads
        f32x4 v = fb4[(size_t)i * TPB + tid];
        acc += wsm[cl + i * CLANES] * v;               // contracts to FMA
    }
    red[tid] = acc;
    __syncthreads();
    if (tid < HW4) {                                   // all in wave 0
        f32x4 s = red[tid];
#pragma unroll
        for (int j = 1; j < CLANES; ++j) s += red[tid + j * HW4];
        ((f32x4*)partial)[(size_t)(b * NCHUNK + k) * HW4 + tid] = s;
    }
    // store above and fence below are both wave 0, program-ordered
    if (tid == 0) {
        __threadfence();                               // release partials
        __hip_atomic_fetch_add(&cnt[b], 1, __ATOMIC_ACQ_REL, __HIP_MEMORY_SCOPE_AGENT);
        while (__hip_atomic_load(&cnt[b], __ATOMIC_RELAXED, __HIP_MEMORY_SCOPE_AGENT) < NCHUNK)
            __builtin_amdgcn_s_sleep(2);
        __threadfence();                               // acquire: drop stale L2 lines
    }
    __syncthreads();

    // ---- Phase 2: redundant per-block reduce of this sample's 16 partials ----
    float v = 0.f;
    if (tid < HWN) {
        const float* pb = partial + (size_t)b * NCHUNK * HWN + tid;
#pragma unroll
        for (int kk = 0; kk < NCHUNK; ++kk) v += pb[kk * HWN];
    }
    float* vals = (float*)red;                         // red is dead; reuse
    if (tid < HWN) vals[tid] = v;
    __syncthreads();
    if (tid < 64) {
        float m0 = vals[tid], m1 = vals[tid + 64], m2 = vals[tid + 128];
        float mn = fminf(m0, fminf(m1, m2));
        float mx = fmaxf(m0, fmaxf(m1, m2));
        for (int off = 32; off > 0; off >>= 1) {
            mn = fminf(mn, __shfl_down(mn, off));
            mx = fmaxf(mx, __shfl_down(mx, off));
        }
        if (tid == 0) { s_mn = mn; s_mx = mx; }
    }
    __syncthreads();
    if (tid < HWN) {
        const float mn = s_mn, mx = s_mx;
        // reference: normalize only if max != 0
        hl[tid] = (mx != 0.f) ? (v - mn) / (mx - mn) : v;
    }
    __syncthreads();

    // ---- Phase 3: scale own chunk (L2/L3-warm) -> out, nontemporal ----
    const f32x4 hv = ((const f32x4*)hl)[hw4];          // loop-invariant
    f32x4* ob4 = (f32x4*)out + base;
#pragma unroll
    for (int i = 0; i < (CCHUNK * HW4) / TPB; ++i) {   // 16 linear iters
        const size_t idx = (size_t)i * TPB + tid;
        f32x4 x = fb4[idx];
        x *= hv;
        __builtin_nontemporal_store(x, &ob4[idx]);     // out never re-read
    }
}

extern "C" void kernel_launch(void* const* d_in, const int* in_sizes, int n_in,
                              void* d_out, int out_size, void* d_ws, size_t ws_size,
                              hipStream_t stream) {
    const float* features = (const float*)d_in[0];   // [64,2048,24,8] f32
    const float* weight   = (const float*)d_in[1];   // [751,2048] f32
    const int*   pids     = (const int*)d_in[2];     // [64] int
    float* out = (float*)d_out;                      // [64,2048,24,8] f32
    float* ws  = (float*)d_ws;

    // zero the 64 arrival counters (256 B)
    hipMemsetAsync((char*)d_ws + CNT_OFF * sizeof(float), 0, BB * sizeof(int), stream);

    fused_kernel<<<BB * NCHUNK, TPB, 0, stream>>>(features, weight, pids, out, ws);
}

// Round 6
// 196.427 us; speedup vs baseline: 1.5758x; 1.5758x over previous
//
#include <hip/hip_runtime.h>

// Problem constants (B, C, H, W = 64, 2048, 24, 8; NUM_IDS = 751)
#define BB 64
#define CC 2048
#define HWN 192          // H*W
#define HW4 48           // HW in float4
#define KCHUNK 8         // channel chunks per sample (kernel 1)
#define CCHUNK 256       // CC / KCHUNK
#define TPB 384          // 8 channel-lanes x 48 hw4 positions; 6 waves/block
#define CLANES 8         // TPB / HW4
#define SCHUNK 16        // scale-kernel chunks per sample
#define SCCH 128         // CC / SCHUNK

// native vector type (HIP float4 is a class; nontemporal builtin needs this)
typedef float f32x4 __attribute__((ext_vector_type(4)));

// ws layout (floats): partial[64*8*192]
#define PART_OFF 0

// ---- Kernel 1: partial heat per (sample, 256-channel chunk) ----
// grid = 512 (b*8 + k), block = 384. 32 independent loads per thread (2x MLP
// vs round 4 -- heat was latency-bound, insensitive to occupancy).
__global__ void __launch_bounds__(TPB) heat_partial_kernel(
    const float* __restrict__ f,
    const float* __restrict__ w,
    const int* __restrict__ pids,
    float* __restrict__ ws)
{
    float* partial = ws + PART_OFF;

    const int blk = blockIdx.x;
    const int b = blk >> 3;            // sample
    const int k = blk & (KCHUNK - 1);  // 256-channel chunk
    const int tid = threadIdx.x;       // 0..383
    const int hw4 = tid % HW4;         // 0..47
    const int cl  = tid / HW4;         // 0..7

    __shared__ float wsm[CCHUNK];
    __shared__ __align__(16) f32x4 red[TPB];

    const int row = pids[b];
    if (tid < CCHUNK) wsm[tid] = w[(size_t)row * CC + (size_t)k * CCHUNK + tid];
    __syncthreads();

    const size_t base = ((size_t)b * CC + (size_t)k * CCHUNK) * HW4;  // f4 units
    const f32x4* fb4 = (const f32x4*)f + base;

    // thread (cl, hw4) accumulates channels cl, cl+8, ..., cl+248
    f32x4 acc = (f32x4)(0.f);
#pragma unroll
    for (int i = 0; i < CCHUNK / CLANES; ++i) {        // 32 linear loads
        f32x4 v = fb4[(size_t)i * TPB + tid];          // lanes consecutive
        acc += wsm[cl + i * CLANES] * v;
    }
    red[tid] = acc;
    __syncthreads();
    if (tid < HW4) {
        f32x4 s = red[tid];
#pragma unroll
        for (int j = 1; j < CLANES; ++j) s += red[tid + j * HW4];
        ((f32x4*)partial)[(size_t)(b * KCHUNK + k) * HW4 + tid] = s;
    }
}

// ---- Kernel 2: fused normalize + scale ----
// grid = 1024 (b*16 + k), block = 384. Prologue: redundant per-block reduce of
// this sample's 8 partials (6 KB, L2/L3-hot), min/max, normalize in LDS.
// Then pure stream: out = f * heatN with nontemporal stores.
__global__ void __launch_bounds__(TPB) norm_scale_kernel(
    const float* __restrict__ f,
    const float* __restrict__ ws,
    float* __restrict__ out)
{
    const float* partial = ws + PART_OFF;

    const int blk = blockIdx.x;
    const int b = blk >> 4;            // sample
    const int k = blk & (SCHUNK - 1);  // 128-channel chunk
    const int tid = threadIdx.x;       // 0..383
    const int hw4 = tid % HW4;

    __shared__ float vals[HWN];
    __shared__ __align__(16) float hl[HWN];
    __shared__ float s_mn, s_mx;

    float v = 0.f;
    if (tid < HWN) {
        const float* pb = partial + (size_t)b * KCHUNK * HWN + tid;
#pragma unroll
        for (int kk = 0; kk < KCHUNK; ++kk) v += pb[kk * HWN];
        vals[tid] = v;
    }
    __syncthreads();
    if (tid < 64) {
        float m0 = vals[tid], m1 = vals[tid + 64], m2 = vals[tid + 128];
        float mn = fminf(m0, fminf(m1, m2));
        float mx = fmaxf(m0, fmaxf(m1, m2));
        for (int off = 32; off > 0; off >>= 1) {
            mn = fminf(mn, __shfl_down(mn, off));
            mx = fmaxf(mx, __shfl_down(mx, off));
        }
        if (tid == 0) { s_mn = mn; s_mx = mx; }
    }
    __syncthreads();
    if (tid < HWN) {
        const float mn = s_mn, mx = s_mx;
        // reference: normalize only if max != 0
        hl[tid] = (mx != 0.f) ? (v - mn) / (mx - mn) : v;
    }
    __syncthreads();

    // stream this block's 128-channel chunk
    const f32x4 hv = ((const f32x4*)hl)[hw4];          // loop-invariant
    const size_t base = ((size_t)b * CC + (size_t)k * SCCH) * HW4;  // f4 units
    const f32x4* fb4 = (const f32x4*)f + base;
    f32x4* ob4 = (f32x4*)out + base;
#pragma unroll
    for (int i = 0; i < (SCCH * HW4) / TPB; ++i) {     // 16 linear iters
        const size_t idx = (size_t)i * TPB + tid;
        f32x4 x = fb4[idx];
        x *= hv;
        __builtin_nontemporal_store(x, &ob4[idx]);     // out never re-read
    }
}

extern "C" void kernel_launch(void* const* d_in, const int* in_sizes, int n_in,
                              void* d_out, int out_size, void* d_ws, size_t ws_size,
                              hipStream_t stream) {
    const float* features = (const float*)d_in[0];   // [64,2048,24,8] f32
    const float* weight   = (const float*)d_in[1];   // [751,2048] f32
    const int*   pids     = (const int*)d_in[2];     // [64] int
    float* out = (float*)d_out;                      // [64,2048,24,8] f32
    float* ws  = (float*)d_ws;

    heat_partial_kernel<<<BB * KCHUNK, TPB, 0, stream>>>(features, weight, pids, ws);
    norm_scale_kernel<<<BB * SCHUNK, TPB, 0, stream>>>(features, ws, out);
}

// Round 7
// 195.647 us; speedup vs baseline: 1.5821x; 1.0040x over previous
//
#include <hip/hip_runtime.h>

// Problem constants (B, C, H, W = 64, 2048, 24, 8; NUM_IDS = 751)
#define BB 64
#define CC 2048
#define HWN 192          // H*W
#define HW4 48           // HW in float4
#define NCHUNK 16        // channel chunks per sample (partial slots)
#define CCHUNK 128       // CC / NCHUNK
// K1 geometry: 2048 small blocks (b, k, half-row), 192 threads, 48 KB/block
#define K1TPB 192
#define K1HW 24          // hw4 positions per block (half row, 384B-aligned)
#define K1CL 8           // channel lanes: 192 / 24
// K2 geometry
#define TPB 384
#define SCHUNK 16        // scale chunks per sample
#define SCCH 128         // CC / SCHUNK

// native vector type (HIP float4 is a class; nontemporal builtin needs this)
typedef float f32x4 __attribute__((ext_vector_type(4)));

// ws layout (floats): partial[64][16][192]  (786 KB, proven-safe size)
#define PART_OFF 0

// ---- Kernel 1: partial heat, fill-like granularity ----
// grid = 2048 (b*32 + k*2 + s), block = 192. Each block: 128 channels x 24 hw4
// (half row) = 48 KB contiguous-per-row reads. Two sibling blocks (s=0,1)
// write disjoint halves of partial[b][k][..] -- no race, same 786 KB layout.
__global__ void __launch_bounds__(K1TPB) heat_partial_kernel(
    const float* __restrict__ f,
    const float* __restrict__ w,
    const int* __restrict__ pids,
    float* __restrict__ ws)
{
    float* partial = ws + PART_OFF;

    const int blk = blockIdx.x;
    const int s = blk & 1;             // row half
    const int k = (blk >> 1) & (NCHUNK - 1);
    const int b = blk >> 5;            // sample
    const int tid = threadIdx.x;       // 0..191
    const int hw = tid % K1HW;         // 0..23
    const int cl = tid / K1HW;         // 0..7

    __shared__ float wsm[CCHUNK];
    __shared__ __align__(16) f32x4 red[K1TPB];

    const int row = pids[b];
    if (tid < CCHUNK) wsm[tid] = w[(size_t)row * CC + (size_t)k * CCHUNK + tid];
    __syncthreads();

    // f4 base of this block's region: sample b, channel k*128, hw4 offset s*24
    const size_t base = ((size_t)b * CC + (size_t)k * CCHUNK) * HW4 + s * K1HW;
    const f32x4* fb4 = (const f32x4*)f + base;

    f32x4 acc = (f32x4)(0.f);
#pragma unroll
    for (int i = 0; i < CCHUNK / K1CL; ++i) {          // 16 loads/thread
        const int c = cl + i * K1CL;                   // channel in chunk
        f32x4 v = fb4[(size_t)c * HW4 + hw];           // 24-f4 runs, line-aligned
        acc += wsm[c] * v;
    }
    red[tid] = acc;
    __syncthreads();
    if (tid < K1HW) {                                  // 24 threads
        f32x4 sum = red[tid];
#pragma unroll
        for (int j = 1; j < K1CL; ++j) sum += red[tid + j * K1HW];
        ((f32x4*)partial)[(size_t)(b * NCHUNK + k) * HW4 + s * K1HW + tid] = sum;
    }
}

// ---- Kernel 2: fused normalize + scale (round-6 structure, at roofline) ----
// grid = 1024 (b*16 + k), block = 384. Prologue: redundant per-block reduce of
// this sample's 16 partials (12 KB, L2/L3-hot), min/max, normalize in LDS.
// Then pure stream: out = f * heatN with nontemporal stores.
__global__ void __launch_bounds__(TPB) norm_scale_kernel(
    const float* __restrict__ f,
    const float* __restrict__ ws,
    float* __restrict__ out)
{
    const float* partial = ws + PART_OFF;

    const int blk = blockIdx.x;
    const int b = blk >> 4;            // sample
    const int k = blk & (SCHUNK - 1);  // 128-channel chunk
    const int tid = threadIdx.x;       // 0..383
    const int hw4 = tid % HW4;

    __shared__ float vals[HWN];
    __shared__ __align__(16) float hl[HWN];
    __shared__ float s_mn, s_mx;

    float v = 0.f;
    if (tid < HWN) {
        const float* pb = partial + (size_t)b * NCHUNK * HWN + tid;
#pragma unroll
        for (int kk = 0; kk < NCHUNK; ++kk) v += pb[kk * HWN];
        vals[tid] = v;
    }
    __syncthreads();
    if (tid < 64) {
        float m0 = vals[tid], m1 = vals[tid + 64], m2 = vals[tid + 128];
        float mn = fminf(m0, fminf(m1, m2));
        float mx = fmaxf(m0, fmaxf(m1, m2));
        for (int off = 32; off > 0; off >>= 1) {
            mn = fminf(mn, __shfl_down(mn, off));
            mx = fmaxf(mx, __shfl_down(mx, off));
        }
        if (tid == 0) { s_mn = mn; s_mx = mx; }
    }
    __syncthreads();
    if (tid < HWN) {
        const float mn = s_mn, mx = s_mx;
        // reference: normalize only if max != 0
        hl[tid] = (mx != 0.f) ? (v - mn) / (mx - mn) : v;
    }
    __syncthreads();

    // stream this block's 128-channel chunk
    const f32x4 hv = ((const f32x4*)hl)[hw4];          // loop-invariant
    const size_t base = ((size_t)b * CC + (size_t)k * SCCH) * HW4;  // f4 units
    const f32x4* fb4 = (const f32x4*)f + base;
    f32x4* ob4 = (f32x4*)out + base;
#pragma unroll
    for (int i = 0; i < (SCCH * HW4) / TPB; ++i) {     // 16 linear iters
        const size_t idx = (size_t)i * TPB + tid;
        f32x4 x = fb4[idx];
        x *= hv;
        __builtin_nontemporal_store(x, &ob4[idx]);     // out never re-read
    }
}

extern "C" void kernel_launch(void* const* d_in, const int* in_sizes, int n_in,
                              void* d_out, int out_size, void* d_ws, size_t ws_size,
                              hipStream_t stream) {
    const float* features = (const float*)d_in[0];   // [64,2048,24,8] f32
    const float* weight   = (const float*)d_in[1];   // [751,2048] f32
    const int*   pids     = (const int*)d_in[2];     // [64] int
    float* out = (float*)d_out;                      // [64,2048,24,8] f32
    float* ws  = (float*)d_ws;

    heat_partial_kernel<<<BB * NCHUNK * 2, K1TPB, 0, stream>>>(features, weight, pids, ws);
    norm_scale_kernel<<<BB * SCHUNK, TPB, 0, stream>>>(features, ws, out);
}